// Round 17
// baseline (586.814 us; speedup 1.0000x reference)
//
#include <hip/hip_runtime.h>
#include <hip/hip_bf16.h>
#include <stdint.h>

#define N_TOK 8192
#define CDIM  1024
#define HDIM  4096
#define NEXP  8
#define BM    128
#define BN    128
#define BK    64

// aux kernel grid layout
#define ZBLK  2048   // zero d_out
#define RBLK  2048   // router: 4 waves/block, 1 token/wave
#define T1BLK 4096   // W1 transpose tiles
#define T2BLK 4096   // W2 transpose tiles

typedef __attribute__((ext_vector_type(8))) short bf16x8;
typedef __attribute__((ext_vector_type(4))) float f32x4;

static __device__ __forceinline__ uint16_t f2bf(float f) {
  union { float f; uint32_t u; } v; v.f = f;
  uint32_t r = v.u + 0x7FFF + ((v.u >> 16) & 1);
  return (uint16_t)(r >> 16);
}

__device__ __forceinline__ void gload_lds16(const void* g, void* l) {
  __builtin_amdgcn_global_load_lds(
      (const __attribute__((address_space(1))) uint32_t*)g,
      (__attribute__((address_space(3))) uint32_t*)l, 16, 0, 0);
}

// transpose+convert one 128(r)x64(c) tile: src [R][S] f32 -> dst [S][R] bf16.
__device__ __forceinline__ void transcvt_tile(const float* __restrict__ src,
                                              uint16_t* __restrict__ dst,
                                              int R, int S, int c0, int r0,
                                              float* tile, int t) {
#pragma unroll
  for (int q = 0; q < 8; q++) {
    int idx = q * 256 + t;
    int row = idx >> 4, s = idx & 15;
    float4 v = *(const float4*)&src[(size_t)(r0 + row) * S + c0 + s * 4];
    *(float4*)&tile[row * 64 + ((s ^ ((row >> 3) & 15)) << 2)] = v;
  }
  __syncthreads();
#pragma unroll
  for (int q = 0; q < 4; q++) {
    int idx = q * 256 + t;
    int crow = idx >> 4, r8 = (idx & 15) * 8;
    bf16x8 o;
#pragma unroll
    for (int k = 0; k < 8; k++) {
      int r = r8 + k;
      o[k] = (short)f2bf(tile[r * 64 + (((crow >> 2) ^ ((r >> 3) & 15)) << 2) + (crow & 3)]);
    }
    *(bf16x8*)&dst[(size_t)(c0 + crow) * R + r0 + r8] = o;
  }
}

// ---- fused aux: zero d_out | router (+x->bf16) | W1 transpose | W2 transpose ----
__global__ __launch_bounds__(256)
void aux_kernel(const float* __restrict__ x, const float* __restrict__ Wr,
                const float* __restrict__ W1, const float* __restrict__ W2,
                uint16_t* __restrict__ xb, uint16_t* __restrict__ W1t,
                uint16_t* __restrict__ W2t, int* __restrict__ te,
                float* __restrict__ tw, float* __restrict__ outz) {
  __shared__ float tile[128 * 64];
  int bid = blockIdx.x;
  int t = threadIdx.x;
  if (bid < ZBLK) {
    float4 z = make_float4(0.f, 0.f, 0.f, 0.f);
    float4* p = (float4*)(outz + ((size_t)bid * 256 + t) * 16);
    p[0] = z; p[1] = z; p[2] = z; p[3] = z;
  } else if (bid < ZBLK + RBLK) {
    int rb = bid - ZBLK;
    int wv = t >> 6, l = t & 63;
    int tok = rb * 4 + wv;
    const float* xr = x + (size_t)tok * CDIM;
    uint16_t* xbr = xb + (size_t)tok * CDIM;
    float p[NEXP];
#pragma unroll
    for (int e = 0; e < NEXP; e++) p[e] = 0.f;
#pragma unroll
    for (int kk = 0; kk < 4; kk++) {
      int o = kk * 256 + l * 4;
      float4 xv = *(const float4*)&xr[o];
      ushort4 s;
      s.x = f2bf(xv.x); s.y = f2bf(xv.y); s.z = f2bf(xv.z); s.w = f2bf(xv.w);
      *(ushort4*)&xbr[o] = s;
#pragma unroll
      for (int e = 0; e < NEXP; e++) {
        float4 w4 = *(const float4*)&Wr[e * CDIM + o];
        p[e] += xv.x * w4.x + xv.y * w4.y + xv.z * w4.z + xv.w * w4.w;
      }
    }
#pragma unroll
    for (int e = 0; e < NEXP; e++) {
      float v = p[e];
#pragma unroll
      for (int s2 = 32; s2 > 0; s2 >>= 1) v += __shfl_xor(v, s2);
      p[e] = v;
    }
    if (l == 0) {
      float m0 = -1e30f, m1 = -1e30f; int i0 = 0, i1 = 0;
#pragma unroll
      for (int e = 0; e < NEXP; e++) {
        float v = p[e];
        if (v > m0) { m1 = m0; i1 = i0; m0 = v; i0 = e; }
        else if (v > m1) { m1 = v; i1 = e; }
      }
      float w0 = 1.f / (1.f + __expf(m1 - m0));
      te[tok] = i0 | (i1 << 16);
      tw[tok] = w0;
    }
  } else if (bid < ZBLK + RBLK + T1BLK) {
    int idx = bid - (ZBLK + RBLK);
    int c = idx & 63, r = (idx >> 6) & 7, e = idx >> 9;
    transcvt_tile(W1 + (size_t)e * CDIM * HDIM, W1t + (size_t)e * CDIM * HDIM,
                  CDIM, HDIM, c * 64, r * 128, tile, t);
  } else {
    int idx = bid - (ZBLK + RBLK + T1BLK);
    int c = idx & 15, r = (idx >> 4) & 31, e = idx >> 9;
    transcvt_tile(W2 + (size_t)e * CDIM * HDIM, W2t + (size_t)e * CDIM * HDIM,
                  HDIM, CDIM, c * 64, r * 128, tile, t);
  }
}

// ---- prefix: count te (register counters); build offs + FULL per-item worklists with
// ---- rb FASTEST (r14-verified: active blocks share one B panel -> L2-resident).
// ---- entry = (e<<20)|(nb<<12)|rb
__global__ void prefix_kernel(const int* __restrict__ te, int* __restrict__ offs,
                              int* __restrict__ fill, int* __restrict__ wk1,
                              int* __restrict__ wk2, int* __restrict__ nwk) {
  int t = threadIdx.x;
  int cc[NEXP];
#pragma unroll
  for (int e = 0; e < NEXP; e++) cc[e] = 0;
  for (int i = t; i < N_TOK; i += 256) {
    int e01 = te[i];
    int e0 = e01 & 0xffff, e1 = e01 >> 16;
#pragma unroll
    for (int e = 0; e < NEXP; e++) cc[e] += (e0 == e) + (e1 == e);
  }
  __shared__ int red[4][NEXP];
  __shared__ int rbn[NEXP], ib1[NEXP + 1], ib2[NEXP + 1];
  int wv = t >> 6, l = t & 63;
#pragma unroll
  for (int e = 0; e < NEXP; e++) {
    int v = cc[e];
#pragma unroll
    for (int s = 32; s > 0; s >>= 1) v += __shfl_xor(v, s);
    if (l == 0) red[wv][e] = v;
  }
  __syncthreads();
  if (t == 0) {
    int acc = 0, a1 = 0, a2 = 0;
    for (int e = 0; e < NEXP; e++) {
      int tot = red[0][e] + red[1][e] + red[2][e] + red[3][e];
      offs[e] = acc; fill[e] = acc; acc += tot;
      rbn[e] = (tot + BM - 1) / BM;
      ib1[e] = a1; a1 += rbn[e] * (HDIM / BN);
      ib2[e] = a2; a2 += rbn[e] * (CDIM / BN);
    }
    offs[NEXP] = acc;
    ib1[NEXP] = a1; ib2[NEXP] = a2;
    nwk[0] = a1; nwk[1] = a2;
  }
  __syncthreads();
  int n1 = ib1[NEXP], n2 = ib2[NEXP];
  for (int i = t; i < n1; i += 256) {
    int e = 0;
    while (i >= ib1[e + 1]) e++;
    int local = i - ib1[e];
    int nb = local / rbn[e], rb = local - nb * rbn[e];
    wk1[i] = (e << 20) | (nb << 12) | rb;
  }
  for (int i = t; i < n2; i += 256) {
    int e = 0;
    while (i >= ib2[e + 1]) e++;
    int local = i - ib2[e];
    int nb = local / rbn[e], rb = local - nb * rbn[e];
    wk2[i] = (e << 20) | (nb << 12) | rb;
  }
}

// ---- bucket: block LDS count -> one reservation atomic/expert/block -> LDS rank ----
__global__ void bucket_kernel(const int* __restrict__ te, const float* __restrict__ tw,
                              int* __restrict__ fill, int* __restrict__ perm,
                              float* __restrict__ pw) {
  __shared__ int bc[NEXP], base[NEXP], rk[NEXP];
  int t = threadIdx.x;
  int tok = blockIdx.x * 256 + t;
  if (t < NEXP) { bc[t] = 0; rk[t] = 0; }
  __syncthreads();
  int e01 = te[tok];
  int e0 = e01 & 0xffff, e1 = e01 >> 16;
  float w0 = tw[tok];
  atomicAdd(&bc[e0], 1);
  atomicAdd(&bc[e1], 1);
  __syncthreads();
  if (t < NEXP) base[t] = atomicAdd(&fill[t], bc[t]);
  __syncthreads();
  int r0 = atomicAdd(&rk[e0], 1);
  perm[base[e0] + r0] = tok; pw[base[e0] + r0] = w0;
  int r1 = atomicAdd(&rk[e1], 1);
  perm[base[e1] + r1] = tok; pw[base[e1] + r1] = 1.f - w0;
}

// ---- grouped GEMM (r14 tile + 8 waves/block): 128x128, BK=64, single-buffered 32KB
// ---- LDS, 512 threads (8 waves, 2Mx4N, wave tile 64x32, acc[4][2]). 4 blocks/CU by
// ---- LDS -> 32 waves/CU = 8 waves/SIMD (r14 had 4/SIMD) = 2x wave-level latency
// ---- hiding during other blocks' barrier drains. NO min-waves bound (r12 spill /
// ---- r15 issue-serialization lessons); VGPR budget at 8 w/EU = 256 >> ~100 needed.
// ---- Serial {STG -> sync -> compute -> sync}; slot^(row&7) swizzle (0 conflicts);
// ---- direct per-item worklist (rb fastest -> B panel L2-resident).
template<bool GATHER, bool RELU2, int NDIM, int KDIM>
__global__ __launch_bounds__(512)
void moe_gemm(const uint16_t* __restrict__ A, const uint16_t* __restrict__ Bt,
              const int* __restrict__ offs, const int* __restrict__ wk,
              const int* __restrict__ nwkp, const int* __restrict__ perm,
              const float* __restrict__ pw, uint16_t* __restrict__ hb,
              float* __restrict__ out) {
  int nitems = nwkp[0];
  int G = gridDim.x;
  int bid = blockIdx.x;
  int b0 = (bid & 7) * (G >> 3) + (bid >> 3);   // XCD gets contiguous item chunk

  __shared__ uint16_t smA[BM * BK];   // 16KB
  __shared__ uint16_t smB[BN * BK];   // 16KB   (32KB total)

  int tid = threadIdx.x;
  int w = tid >> 6, l = tid & 63;
  int wr = w >> 2, wc = w & 3;           // 2M x 4N waves, wave tile 64x32
  int cl = l & 15, kh = l >> 4;
  int rg = kh * 4;

  for (int item = b0; item < nitems; item += G) {
    int pr = wk[item];
    int e = pr >> 20;
    int nb0 = ((pr >> 12) & 255) * BN;
    int rb = (pr & 4095) * BM;
    int o0 = offs[e];
    int Me = offs[e + 1] - o0;

    // staging pointers: chunk c = j*512+tid (j<2) -> row = c>>3, slot = c&7;
    // source k-chunk = slot ^ (row&7) (swizzle folded into source, linear LDS dest)
    const uint16_t* aptr[2];
#pragma unroll
    for (int j = 0; j < 2; j++) {
      int c = j * 512 + tid;
      int row = c >> 3, slot = c & 7;
      int gi = o0 + rb + row;
      if (gi > 2 * N_TOK - 1) gi = 2 * N_TOK - 1;
      int ar = GATHER ? perm[gi] : gi;
      aptr[j] = A + (size_t)ar * KDIM + ((slot ^ (row & 7)) << 3);
    }
    const uint16_t* bb = Bt + (size_t)e * NDIM * KDIM;
    const uint16_t* bptr[2];
#pragma unroll
    for (int j = 0; j < 2; j++) {
      int c = j * 512 + tid;
      int row = c >> 3, slot = c & 7;
      bptr[j] = bb + (size_t)(nb0 + row) * KDIM + ((slot ^ (row & 7)) << 3);
    }

    f32x4 acc[4][2];
#pragma unroll
    for (int m = 0; m < 4; m++)
#pragma unroll
      for (int n = 0; n < 2; n++)
        acc[m][n] = (f32x4)0.f;

#define LDSF(base, row, s) \
    (*(const bf16x8*)&(base)[(row) * BK + ((((s) ^ ((row) & 7))) << 3)])

    const int NT = KDIM / BK;
    for (int t = 0; t < NT; ++t) {
#pragma unroll
      for (int j = 0; j < 2; j++) {
        gload_lds16(aptr[j] + t * BK, (char*)&smA[0] + j * 8192 + tid * 16);
        gload_lds16(bptr[j] + t * BK, (char*)&smB[0] + j * 8192 + tid * 16);
      }
      __syncthreads();   // tile fully staged

      bf16x8 af[4][2], bf[2][2];
#pragma unroll
      for (int n = 0; n < 2; n++)
#pragma unroll
        for (int kk = 0; kk < 2; kk++)
          bf[n][kk] = LDSF(smB, wc * 32 + n * 16 + cl, kk * 4 + kh);
#pragma unroll
      for (int m = 0; m < 4; m++)
#pragma unroll
        for (int kk = 0; kk < 2; kk++)
          af[m][kk] = LDSF(smA, wr * 64 + m * 16 + cl, kk * 4 + kh);
#pragma unroll
      for (int m = 0; m < 4; m++)
#pragma unroll
        for (int n = 0; n < 2; n++) {
          acc[m][n] = __builtin_amdgcn_mfma_f32_16x16x32_bf16(af[m][0], bf[n][0], acc[m][n], 0, 0, 0);
          acc[m][n] = __builtin_amdgcn_mfma_f32_16x16x32_bf16(af[m][1], bf[n][1], acc[m][n], 0, 0, 0);
        }
      __syncthreads();   // reads done before next tile's staging overwrites
    }
#undef LDSF

    if (RELU2) {
#pragma unroll
      for (int m = 0; m < 4; m++) {
#pragma unroll
        for (int jj = 0; jj < 4; jj++) {
          int er = rb + wr * 64 + m * 16 + rg + jj;
          if (er < Me) {
            size_t rowoff = (size_t)(o0 + er) * NDIM;
#pragma unroll
            for (int n = 0; n < 2; n++) {
              int gc = nb0 + wc * 32 + n * 16 + cl;
              float v = acc[m][n][jj];
              v = v > 0.f ? v * v : 0.f;
              hb[rowoff + gc] = f2bf(v);
            }
          }
        }
      }
    } else {
#pragma unroll
      for (int m = 0; m < 4; m++) {
#pragma unroll
        for (int jj = 0; jj < 4; jj++) {
          int er = rb + wr * 64 + m * 16 + rg + jj;
          if (er < Me) {
            int gi = o0 + er;
            int tok = perm[gi];
            float wgt = pw[gi];
            size_t rowoff = (size_t)tok * NDIM;
#pragma unroll
            for (int n = 0; n < 2; n++) {
              int gc = nb0 + wc * 32 + n * 16 + cl;
              atomicAdd(&out[rowoff + gc], wgt * acc[m][n][jj]);
            }
          }
        }
      }
    }
  }
}

extern "C" void kernel_launch(void* const* d_in, const int* in_sizes, int n_in,
                              void* d_out, int out_size, void* d_ws, size_t ws_size,
                              hipStream_t stream) {
  const float* x  = (const float*)d_in[0];
  const float* Wr = (const float*)d_in[1];
  const float* W1 = (const float*)d_in[2];
  const float* W2 = (const float*)d_in[3];
  float* out = (float*)d_out;

  char* ws = (char*)d_ws;
  size_t off = 0;
  uint16_t* xb  = (uint16_t*)(ws + off); off += (size_t)N_TOK * CDIM * 2;
  uint16_t* W1t = (uint16_t*)(ws + off); off += (size_t)NEXP * CDIM * HDIM * 2;
  uint16_t* W2t = (uint16_t*)(ws + off); off += (size_t)NEXP * CDIM * HDIM * 2;
  uint16_t* hb  = (uint16_t*)(ws + off); off += (size_t)2 * N_TOK * HDIM * 2;
  int*   perm = (int*)(ws + off); off += (size_t)2 * N_TOK * 4;
  float* pwt  = (float*)(ws + off); off += (size_t)2 * N_TOK * 4;
  int*   te   = (int*)(ws + off); off += (size_t)N_TOK * 4;
  float* tw   = (float*)(ws + off); off += (size_t)N_TOK * 4;
  int*   offs = (int*)(ws + off); off += 16 * 4;
  int*   fill = (int*)(ws + off); off += 16 * 4;
  int*   wk1  = (int*)(ws + off); off += 6144 * 4;
  int*   wk2  = (int*)(ws + off); off += 2048 * 4;
  int*   nwk  = (int*)(ws + off); off += 16 * 4;

  // 1) fused aux: zero out | router | W1^T | W2^T
  aux_kernel<<<ZBLK + RBLK + T1BLK + T2BLK, 256, 0, stream>>>(
      x, Wr, W1, W2, xb, W1t, W2t, te, tw, out);
  // 2) count + offsets + per-item worklists (rb fastest)
  prefix_kernel<<<1, 256, 0, stream>>>(te, offs, fill, wk1, wk2, nwk);
  // 3) bucket tokens into per-expert groups
  bucket_kernel<<<N_TOK / 256, 256, 0, stream>>>(te, tw, fill, perm, pwt);
  // 4) GEMM1: h = relu^2(x @ W1)  [gathered]  items ~= 4300, ~2/block
  moe_gemm<true, true, HDIM, CDIM><<<2048, 512, 0, stream>>>(
      xb, W1t, offs, wk1, &nwk[0], perm, pwt, hb, out);
  // 5) GEMM2: out += gate * (h @ W2)  items ~= 1080, ~1/block
  moe_gemm<false, false, CDIM, HDIM><<<1088, 512, 0, stream>>>(
      hb, W2t, offs, wk2, &nwk[1], perm, pwt, hb, out);
}

// Round 18
// 506.057 us; speedup vs baseline: 1.1596x; 1.1596x over previous
//
#include <hip/hip_runtime.h>
#include <hip/hip_bf16.h>
#include <stdint.h>

#define N_TOK 8192
#define CDIM  1024
#define HDIM  4096
#define NEXP  8
#define BM    128
#define BN    128
#define BK    64

// aux kernel grid layout
#define ZBLK  2048   // zero d_out
#define RBLK  2048   // router: 4 waves/block, 1 token/wave
#define T1BLK 4096   // W1 transpose tiles
#define T2BLK 4096   // W2 transpose tiles

typedef __attribute__((ext_vector_type(8))) short bf16x8;
typedef __attribute__((ext_vector_type(4))) float f32x4;

static __device__ __forceinline__ uint16_t f2bf(float f) {
  union { float f; uint32_t u; } v; v.f = f;
  uint32_t r = v.u + 0x7FFF + ((v.u >> 16) & 1);
  return (uint16_t)(r >> 16);
}

__device__ __forceinline__ void gload_lds16(const void* g, void* l) {
  __builtin_amdgcn_global_load_lds(
      (const __attribute__((address_space(1))) uint32_t*)g,
      (__attribute__((address_space(3))) uint32_t*)l, 16, 0, 0);
}

// transpose+convert one 128(r)x64(c) tile: src [R][S] f32 -> dst [S][R] bf16.
__device__ __forceinline__ void transcvt_tile(const float* __restrict__ src,
                                              uint16_t* __restrict__ dst,
                                              int R, int S, int c0, int r0,
                                              float* tile, int t) {
#pragma unroll
  for (int q = 0; q < 8; q++) {
    int idx = q * 256 + t;
    int row = idx >> 4, s = idx & 15;
    float4 v = *(const float4*)&src[(size_t)(r0 + row) * S + c0 + s * 4];
    *(float4*)&tile[row * 64 + ((s ^ ((row >> 3) & 15)) << 2)] = v;
  }
  __syncthreads();
#pragma unroll
  for (int q = 0; q < 4; q++) {
    int idx = q * 256 + t;
    int crow = idx >> 4, r8 = (idx & 15) * 8;
    bf16x8 o;
#pragma unroll
    for (int k = 0; k < 8; k++) {
      int r = r8 + k;
      o[k] = (short)f2bf(tile[r * 64 + (((crow >> 2) ^ ((r >> 3) & 15)) << 2) + (crow & 3)]);
    }
    *(bf16x8*)&dst[(size_t)(c0 + crow) * R + r0 + r8] = o;
  }
}

// ---- fused aux: zero d_out | router (+x->bf16) | W1 transpose | W2 transpose ----
__global__ __launch_bounds__(256)
void aux_kernel(const float* __restrict__ x, const float* __restrict__ Wr,
                const float* __restrict__ W1, const float* __restrict__ W2,
                uint16_t* __restrict__ xb, uint16_t* __restrict__ W1t,
                uint16_t* __restrict__ W2t, int* __restrict__ te,
                float* __restrict__ tw, float* __restrict__ outz) {
  __shared__ float tile[128 * 64];
  int bid = blockIdx.x;
  int t = threadIdx.x;
  if (bid < ZBLK) {
    float4 z = make_float4(0.f, 0.f, 0.f, 0.f);
    float4* p = (float4*)(outz + ((size_t)bid * 256 + t) * 16);
    p[0] = z; p[1] = z; p[2] = z; p[3] = z;
  } else if (bid < ZBLK + RBLK) {
    int rb = bid - ZBLK;
    int wv = t >> 6, l = t & 63;
    int tok = rb * 4 + wv;
    const float* xr = x + (size_t)tok * CDIM;
    uint16_t* xbr = xb + (size_t)tok * CDIM;
    float p[NEXP];
#pragma unroll
    for (int e = 0; e < NEXP; e++) p[e] = 0.f;
#pragma unroll
    for (int kk = 0; kk < 4; kk++) {
      int o = kk * 256 + l * 4;
      float4 xv = *(const float4*)&xr[o];
      ushort4 s;
      s.x = f2bf(xv.x); s.y = f2bf(xv.y); s.z = f2bf(xv.z); s.w = f2bf(xv.w);
      *(ushort4*)&xbr[o] = s;
#pragma unroll
      for (int e = 0; e < NEXP; e++) {
        float4 w4 = *(const float4*)&Wr[e * CDIM + o];
        p[e] += xv.x * w4.x + xv.y * w4.y + xv.z * w4.z + xv.w * w4.w;
      }
    }
#pragma unroll
    for (int e = 0; e < NEXP; e++) {
      float v = p[e];
#pragma unroll
      for (int s2 = 32; s2 > 0; s2 >>= 1) v += __shfl_xor(v, s2);
      p[e] = v;
    }
    if (l == 0) {
      float m0 = -1e30f, m1 = -1e30f; int i0 = 0, i1 = 0;
#pragma unroll
      for (int e = 0; e < NEXP; e++) {
        float v = p[e];
        if (v > m0) { m1 = m0; i1 = i0; m0 = v; i0 = e; }
        else if (v > m1) { m1 = v; i1 = e; }
      }
      float w0 = 1.f / (1.f + __expf(m1 - m0));
      te[tok] = i0 | (i1 << 16);
      tw[tok] = w0;
    }
  } else if (bid < ZBLK + RBLK + T1BLK) {
    int idx = bid - (ZBLK + RBLK);
    int c = idx & 63, r = (idx >> 6) & 7, e = idx >> 9;
    transcvt_tile(W1 + (size_t)e * CDIM * HDIM, W1t + (size_t)e * CDIM * HDIM,
                  CDIM, HDIM, c * 64, r * 128, tile, t);
  } else {
    int idx = bid - (ZBLK + RBLK + T1BLK);
    int c = idx & 15, r = (idx >> 4) & 31, e = idx >> 9;
    transcvt_tile(W2 + (size_t)e * CDIM * HDIM, W2t + (size_t)e * CDIM * HDIM,
                  HDIM, CDIM, c * 64, r * 128, tile, t);
  }
}

// ---- prefix: count te (register counters); build offs + FULL per-item worklists with
// ---- rb FASTEST (r14-verified: active blocks share one B panel -> L2-resident).
// ---- entry = (e<<20)|(nb<<12)|rb
__global__ void prefix_kernel(const int* __restrict__ te, int* __restrict__ offs,
                              int* __restrict__ fill, int* __restrict__ wk1,
                              int* __restrict__ wk2, int* __restrict__ nwk) {
  int t = threadIdx.x;
  int cc[NEXP];
#pragma unroll
  for (int e = 0; e < NEXP; e++) cc[e] = 0;
  for (int i = t; i < N_TOK; i += 256) {
    int e01 = te[i];
    int e0 = e01 & 0xffff, e1 = e01 >> 16;
#pragma unroll
    for (int e = 0; e < NEXP; e++) cc[e] += (e0 == e) + (e1 == e);
  }
  __shared__ int red[4][NEXP];
  __shared__ int rbn[NEXP], ib1[NEXP + 1], ib2[NEXP + 1];
  int wv = t >> 6, l = t & 63;
#pragma unroll
  for (int e = 0; e < NEXP; e++) {
    int v = cc[e];
#pragma unroll
    for (int s = 32; s > 0; s >>= 1) v += __shfl_xor(v, s);
    if (l == 0) red[wv][e] = v;
  }
  __syncthreads();
  if (t == 0) {
    int acc = 0, a1 = 0, a2 = 0;
    for (int e = 0; e < NEXP; e++) {
      int tot = red[0][e] + red[1][e] + red[2][e] + red[3][e];
      offs[e] = acc; fill[e] = acc; acc += tot;
      rbn[e] = (tot + BM - 1) / BM;
      ib1[e] = a1; a1 += rbn[e] * (HDIM / BN);
      ib2[e] = a2; a2 += rbn[e] * (CDIM / BN);
    }
    offs[NEXP] = acc;
    ib1[NEXP] = a1; ib2[NEXP] = a2;
    nwk[0] = a1; nwk[1] = a2;
  }
  __syncthreads();
  int n1 = ib1[NEXP], n2 = ib2[NEXP];
  for (int i = t; i < n1; i += 256) {
    int e = 0;
    while (i >= ib1[e + 1]) e++;
    int local = i - ib1[e];
    int nb = local / rbn[e], rb = local - nb * rbn[e];
    wk1[i] = (e << 20) | (nb << 12) | rb;
  }
  for (int i = t; i < n2; i += 256) {
    int e = 0;
    while (i >= ib2[e + 1]) e++;
    int local = i - ib2[e];
    int nb = local / rbn[e], rb = local - nb * rbn[e];
    wk2[i] = (e << 20) | (nb << 12) | rb;
  }
}

// ---- bucket: block LDS count -> one reservation atomic/expert/block -> LDS rank ----
__global__ void bucket_kernel(const int* __restrict__ te, const float* __restrict__ tw,
                              int* __restrict__ fill, int* __restrict__ perm,
                              float* __restrict__ pw) {
  __shared__ int bc[NEXP], base[NEXP], rk[NEXP];
  int t = threadIdx.x;
  int tok = blockIdx.x * 256 + t;
  if (t < NEXP) { bc[t] = 0; rk[t] = 0; }
  __syncthreads();
  int e01 = te[tok];
  int e0 = e01 & 0xffff, e1 = e01 >> 16;
  float w0 = tw[tok];
  atomicAdd(&bc[e0], 1);
  atomicAdd(&bc[e1], 1);
  __syncthreads();
  if (t < NEXP) base[t] = atomicAdd(&fill[t], bc[t]);
  __syncthreads();
  int r0 = atomicAdd(&rk[e0], 1);
  perm[base[e0] + r0] = tok; pw[base[e0] + r0] = w0;
  int r1 = atomicAdd(&rk[e1], 1);
  perm[base[e1] + r1] = tok; pw[base[e1] + r1] = 1.f - w0;
}

// ---- grouped GEMM (r14 proven best, final): 128x128, BK=64, single-buffered 32KB LDS,
// ---- serial {STG -> sync -> compute -> sync}; slot^(row&7) swizzle (0 conflicts);
// ---- __launch_bounds__(256,4): 4 blocks/CU, VGPR 64, no spill.
// ---- REFUTED alternatives (do not retry): (256,5) -> VGPR 48, staging serialized,
// ---- 2.3x slower (r15); (512,6) -> acc spilled (r12); 512-thread 8-wave same tile ->
// ---- half wave-tile, LDS-port contention, -26% (r17); 256^2 tiles at 1 block/CU ->
// ---- lockstep serialization, all schedules ~330us (r2-r6, r10); 128x256 -> L2
// ---- thrash (r13). Direct per-item worklist (rb fastest -> B panel L2-resident).
template<bool GATHER, bool RELU2, int NDIM, int KDIM>
__global__ __launch_bounds__(256, 4)
void moe_gemm(const uint16_t* __restrict__ A, const uint16_t* __restrict__ Bt,
              const int* __restrict__ offs, const int* __restrict__ wk,
              const int* __restrict__ nwkp, const int* __restrict__ perm,
              const float* __restrict__ pw, uint16_t* __restrict__ hb,
              float* __restrict__ out) {
  int nitems = nwkp[0];
  int G = gridDim.x;
  int bid = blockIdx.x;
  int b0 = (bid & 7) * (G >> 3) + (bid >> 3);   // XCD gets contiguous item chunk

  __shared__ uint16_t smA[BM * BK];   // 16KB
  __shared__ uint16_t smB[BN * BK];   // 16KB   (32KB total)

  int tid = threadIdx.x;
  int w = tid >> 6, l = tid & 63;
  int wr = w >> 1, wc = w & 1;           // 2x2 waves, wave tile 64x64
  int cl = l & 15, kh = l >> 4;
  int rg = kh * 4;

  for (int item = b0; item < nitems; item += G) {
    int pr = wk[item];
    int e = pr >> 20;
    int nb0 = ((pr >> 12) & 255) * BN;
    int rb = (pr & 4095) * BM;
    int o0 = offs[e];
    int Me = offs[e + 1] - o0;

    const uint16_t* aptr[4];
#pragma unroll
    for (int j = 0; j < 4; j++) {
      int c = j * 256 + tid;
      int row = c >> 3, slot = c & 7;
      int gi = o0 + rb + row;
      if (gi > 2 * N_TOK - 1) gi = 2 * N_TOK - 1;
      int ar = GATHER ? perm[gi] : gi;
      aptr[j] = A + (size_t)ar * KDIM + ((slot ^ (row & 7)) << 3);
    }
    const uint16_t* bb = Bt + (size_t)e * NDIM * KDIM;
    const uint16_t* bptr[4];
#pragma unroll
    for (int j = 0; j < 4; j++) {
      int c = j * 256 + tid;
      int row = c >> 3, slot = c & 7;
      bptr[j] = bb + (size_t)(nb0 + row) * KDIM + ((slot ^ (row & 7)) << 3);
    }

    f32x4 acc[4][4];
#pragma unroll
    for (int m = 0; m < 4; m++)
#pragma unroll
      for (int n = 0; n < 4; n++)
        acc[m][n] = (f32x4)0.f;

#define LDSF(base, row, s) \
    (*(const bf16x8*)&(base)[(row) * BK + ((((s) ^ ((row) & 7))) << 3)])

    const int NT = KDIM / BK;
    for (int t = 0; t < NT; ++t) {
#pragma unroll
      for (int j = 0; j < 4; j++) {
        gload_lds16(aptr[j] + t * BK, (char*)&smA[0] + j * 4096 + tid * 16);
        gload_lds16(bptr[j] + t * BK, (char*)&smB[0] + j * 4096 + tid * 16);
      }
      __syncthreads();   // tile fully staged

      bf16x8 af[4][2], bf[4][2];
#pragma unroll
      for (int n = 0; n < 4; n++)
#pragma unroll
        for (int kk = 0; kk < 2; kk++)
          bf[n][kk] = LDSF(smB, wc * 64 + n * 16 + cl, kk * 4 + kh);
#pragma unroll
      for (int m = 0; m < 4; m++)
#pragma unroll
        for (int kk = 0; kk < 2; kk++)
          af[m][kk] = LDSF(smA, wr * 64 + m * 16 + cl, kk * 4 + kh);
#pragma unroll
      for (int m = 0; m < 4; m++)
#pragma unroll
        for (int n = 0; n < 4; n++) {
          acc[m][n] = __builtin_amdgcn_mfma_f32_16x16x32_bf16(af[m][0], bf[n][0], acc[m][n], 0, 0, 0);
          acc[m][n] = __builtin_amdgcn_mfma_f32_16x16x32_bf16(af[m][1], bf[n][1], acc[m][n], 0, 0, 0);
        }
      __syncthreads();   // reads done before next tile's staging overwrites
    }
#undef LDSF

    if (RELU2) {
#pragma unroll
      for (int m = 0; m < 4; m++) {
#pragma unroll
        for (int jj = 0; jj < 4; jj++) {
          int er = rb + wr * 64 + m * 16 + rg + jj;
          if (er < Me) {
            size_t rowoff = (size_t)(o0 + er) * NDIM;
#pragma unroll
            for (int n = 0; n < 4; n++) {
              int gc = nb0 + wc * 64 + n * 16 + cl;
              float v = acc[m][n][jj];
              v = v > 0.f ? v * v : 0.f;
              hb[rowoff + gc] = f2bf(v);
            }
          }
        }
      }
    } else {
#pragma unroll
      for (int m = 0; m < 4; m++) {
#pragma unroll
        for (int jj = 0; jj < 4; jj++) {
          int er = rb + wr * 64 + m * 16 + rg + jj;
          if (er < Me) {
            int gi = o0 + er;
            int tok = perm[gi];
            float wgt = pw[gi];
            size_t rowoff = (size_t)tok * NDIM;
#pragma unroll
            for (int n = 0; n < 4; n++) {
              int gc = nb0 + wc * 64 + n * 16 + cl;
              atomicAdd(&out[rowoff + gc], wgt * acc[m][n][jj]);
            }
          }
        }
      }
    }
  }
}

extern "C" void kernel_launch(void* const* d_in, const int* in_sizes, int n_in,
                              void* d_out, int out_size, void* d_ws, size_t ws_size,
                              hipStream_t stream) {
  const float* x  = (const float*)d_in[0];
  const float* Wr = (const float*)d_in[1];
  const float* W1 = (const float*)d_in[2];
  const float* W2 = (const float*)d_in[3];
  float* out = (float*)d_out;

  char* ws = (char*)d_ws;
  size_t off = 0;
  uint16_t* xb  = (uint16_t*)(ws + off); off += (size_t)N_TOK * CDIM * 2;
  uint16_t* W1t = (uint16_t*)(ws + off); off += (size_t)NEXP * CDIM * HDIM * 2;
  uint16_t* W2t = (uint16_t*)(ws + off); off += (size_t)NEXP * CDIM * HDIM * 2;
  uint16_t* hb  = (uint16_t*)(ws + off); off += (size_t)2 * N_TOK * HDIM * 2;
  int*   perm = (int*)(ws + off); off += (size_t)2 * N_TOK * 4;
  float* pwt  = (float*)(ws + off); off += (size_t)2 * N_TOK * 4;
  int*   te   = (int*)(ws + off); off += (size_t)N_TOK * 4;
  float* tw   = (float*)(ws + off); off += (size_t)N_TOK * 4;
  int*   offs = (int*)(ws + off); off += 16 * 4;
  int*   fill = (int*)(ws + off); off += 16 * 4;
  int*   wk1  = (int*)(ws + off); off += 6144 * 4;
  int*   wk2  = (int*)(ws + off); off += 2048 * 4;
  int*   nwk  = (int*)(ws + off); off += 16 * 4;

  // 1) fused aux: zero out | router | W1^T | W2^T
  aux_kernel<<<ZBLK + RBLK + T1BLK + T2BLK, 256, 0, stream>>>(
      x, Wr, W1, W2, xb, W1t, W2t, te, tw, out);
  // 2) count + offsets + per-item worklists (rb fastest)
  prefix_kernel<<<1, 256, 0, stream>>>(te, offs, fill, wk1, wk2, nwk);
  // 3) bucket tokens into per-expert groups
  bucket_kernel<<<N_TOK / 256, 256, 0, stream>>>(te, tw, fill, perm, pwt);
  // 4) GEMM1: h = relu^2(x @ W1)  [gathered]  items ~= 4300
  moe_gemm<true, true, HDIM, CDIM><<<4352, 256, 0, stream>>>(
      xb, W1t, offs, wk1, &nwk[0], perm, pwt, hb, out);
  // 5) GEMM2: out += gate * (h @ W2)  items ~= 1080
  moe_gemm<false, false, CDIM, HDIM><<<1088, 256, 0, stream>>>(
      hb, W2t, offs, wk2, &nwk[1], perm, pwt, hb, out);
}